// Round 13
// baseline (268.070 us; speedup 1.0000x reference)
//
#include <hip/hip_runtime.h>
#include <hip/hip_bf16.h>
#include <stdint.h>

// Problem constants
#define BB   2
#define CIN  32
#define COUT 16
#define DD   48
#define HIN  64
#define WIN  128
#define H2   128   // 2*HIN
#define W2   256   // 2*WIN
#define PLANE_WORDS (H2 * W2)   // 32768 sign-words per (b,d) plane

// ---------------------------------------------------------------------------
// prep: pack weight signs and fold alpha into BN scale/shift.
// ---------------------------------------------------------------------------
__global__ __launch_bounds__(512) void ibc3d_prep(
    const float* __restrict__ wgt, const float* __restrict__ gamma,
    const float* __restrict__ beta, const float* __restrict__ rmean,
    const float* __restrict__ rvar, uint32_t* __restrict__ bw,
    float* __restrict__ scale, float* __restrict__ shift)
{
    int t = threadIdx.x;
    if (t < 27 * 16) {
        int tap = t >> 4, co = t & 15;
        uint32_t word = 0;
        for (int ci = 0; ci < CIN; ++ci) {
            float v = wgt[(co * CIN + ci) * 27 + tap];
            word |= (v > 0.0f ? 1u : 0u) << ci;
        }
        bw[t] = word;
    }
    // alpha: 16 co x 32 lanes; 864 = 32*27 elements each
    {
        int co   = t >> 5;          // [0,16)
        int lane = t & 31;
        double p = 0.0;
        for (int k = 0; k < 27; ++k)
            p += fabs((double)wgt[co * (CIN * 27) + lane + 32 * k]);
#pragma unroll
        for (int s = 16; s >= 1; s >>= 1)
            p += __shfl_down(p, s, 32);
        if (lane == 0) {
            float alpha = (float)(p / (double)(CIN * 27));
            float inv = gamma[co] / sqrtf(rvar[co] + 1e-5f);
            scale[co] = alpha * inv;
            shift[co] = beta[co] - rmean[co] * inv;
        }
    }
}

// ---------------------------------------------------------------------------
// pack_word (exact fp64 path, used by fused fallback only).
// ---------------------------------------------------------------------------
__device__ __forceinline__ uint32_t pack_word(const float* __restrict__ x,
                                              int b, int d, int h2, int w2)
{
    int m = h2 >> 1, dh = h2 & 1;
    int n = w2 >> 1, dwp = w2 & 1;
    int rA = m + dh - 1;
    int rB = rA + 1;
    double wA = dh ? 0.75 : 0.25;
    double wB = 1.0 - wA;
    rA = rA < 0 ? 0 : rA;
    rB = rB > (HIN - 1) ? (HIN - 1) : rB;
    int cA = n + dwp - 1;
    int cB = cA + 1;
    double wC = dwp ? 0.75 : 0.25;
    double wD = 1.0 - wC;
    cA = cA < 0 ? 0 : cA;
    cB = cB > (WIN - 1) ? (WIN - 1) : cB;

    const float* xp = x + ((size_t)b * CIN * DD + d) * (HIN * WIN);
    int oA = rA * WIN, oB = rB * WIN;
    uint32_t word = 0;
    for (int ci = 0; ci < CIN; ++ci) {
        const float* xc = xp + (size_t)ci * (DD * HIN * WIN);
        float a0 = xc[oA + cA], a1 = xc[oA + cB];
        float b0 = xc[oB + cA], b1 = xc[oB + cB];
        double t0 = wA * (double)a0 + wB * (double)b0;
        double t1 = wA * (double)a1 + wB * (double)b1;
        double v  = wC * t0 + wD * t1;
        word |= (v >= 0.0 ? 1u : 0u) << ci;
    }
    return word;
}

// ---------------------------------------------------------------------------
// packr8 (round-12 code, REP-instrumented): one thread packs 1 row x 8 cols.
// REP>1 repeats the identical computation (idempotent) so the dispatch runs
// long enough to appear in rocprof's top-5 — counters for THIS kernel.
// ---------------------------------------------------------------------------
template <int REP>
__global__ __launch_bounds__(256) void ibc3d_packr8(
    const float* __restrict__ x, uint32_t* __restrict__ bx,
    int b_start, int nplanes)
{
    int per = gridDim.x >> 3;
    int bid = (blockIdx.x & 7) * per + (blockIdx.x >> 3);
    int idx = bid * 256 + threadIdx.x;   // [0, nplanes*4096)
    int j  = idx & 31;               // 8-col group [0,32)
    int h2 = (idx >> 5) & (H2 - 1);  // output row [0,128)
    int pl = idx >> 12;              // local plane
    if (pl >= nplanes) return;
    int d  = pl % DD;
    int b  = b_start + pl / DD;

#pragma unroll 1
    for (int rep = 0; rep < REP; ++rep) {
    int m = h2 >> 1, q = h2 & 1;
    int rT = q ? m : (m > 0 ? m - 1 : 0);
    int rB = q ? (m < HIN - 1 ? m + 1 : HIN - 1) : m;
    float wT = q ? 0.75f : 0.25f;
    float wB = 1.0f - wT;

    int c0 = 4 * j;
    int cl = c0 >= 2 ? c0 - 2 : 0;
    int cr = (c0 + 4 <= WIN - 2) ? c0 + 4 : WIN - 2;

    const float* xp = x + ((size_t)b * CIN * DD + d) * (HIN * WIN);
    int oT = rT * WIN, oB2 = rB * WIN;

    uint32_t w[8];
#pragma unroll
    for (int k = 0; k < 8; ++k) w[k] = 0u;

#pragma unroll 2
    for (int ci = 0; ci < CIN; ++ci) {
        const float* xc = xp + (size_t)ci * (DD * HIN * WIN);
        float cT[6], cB[6];
        {
            const float* rowT = xc + oT;
            float2 L = *(const float2*)(rowT + cl);
            float4 M = *(const float4*)(rowT + c0);
            float2 R = *(const float2*)(rowT + cr);
            cT[0] = (j > 0)  ? L.y : L.x;
            cT[1] = M.x; cT[2] = M.y; cT[3] = M.z; cT[4] = M.w;
            cT[5] = (j < 31) ? R.x : R.y;
        }
        {
            const float* rowB = xc + oB2;
            float2 L = *(const float2*)(rowB + cl);
            float4 M = *(const float4*)(rowB + c0);
            float2 R = *(const float2*)(rowB + cr);
            cB[0] = (j > 0)  ? L.y : L.x;
            cB[1] = M.x; cB[2] = M.y; cB[3] = M.z; cB[4] = M.w;
            cB[5] = (j < 31) ? R.x : R.y;
        }

        float v[8];
#pragma unroll
        for (int t = 0; t < 4; ++t) {
            float uT0 = 0.25f * cT[t]     + 0.75f * cT[t + 1];
            float uT1 = 0.75f * cT[t + 1] + 0.25f * cT[t + 2];
            float uB0 = 0.25f * cB[t]     + 0.75f * cB[t + 1];
            float uB1 = 0.75f * cB[t + 1] + 0.25f * cB[t + 2];
            v[2 * t]     = wT * uT0 + wB * uB0;
            v[2 * t + 1] = wT * uT1 + wB * uB1;
        }

        float amin = 3.4e38f;
#pragma unroll
        for (int k = 0; k < 8; ++k)
            amin = fminf(amin, fabsf(v[k]));

        if (__builtin_expect(amin < 1e-5f, 0)) {
            double dwT = (double)wT, dwB = 1.0 - (double)wT;
#pragma unroll
            for (int t = 0; t < 4; ++t) {
                double eT0 = 0.25 * (double)cT[t]     + 0.75 * (double)cT[t + 1];
                double eT1 = 0.75 * (double)cT[t + 1] + 0.25 * (double)cT[t + 2];
                double eB0 = 0.25 * (double)cB[t]     + 0.75 * (double)cB[t + 1];
                double eB1 = 0.75 * (double)cB[t + 1] + 0.25 * (double)cB[t + 2];
                uint32_t s0 = (dwT * eT0 + dwB * eB0) >= 0.0;
                uint32_t s1 = (dwT * eT1 + dwB * eB1) >= 0.0;
                w[2 * t]     |= s0 << ci;
                w[2 * t + 1] |= s1 << ci;
            }
        } else {
#pragma unroll
            for (int k = 0; k < 8; ++k)
                w[k] |= (v[k] >= 0.0f ? 1u : 0u) << ci;
        }
    }

    size_t base = (size_t)pl * PLANE_WORDS + (size_t)h2 * W2 + 8 * j;
    *(uint4*)(bx + base)     = make_uint4(w[0], w[1], w[2], w[3]);
    *(uint4*)(bx + base + 4) = make_uint4(w[4], w[5], w[6], w[7]);
    }  // rep
}

// ---------------------------------------------------------------------------
// conv6 (round-12 code, REP-instrumented).
// ---------------------------------------------------------------------------
template <int REP>
__global__ __launch_bounds__(256) void ibc3d_conv6(
    const uint32_t* __restrict__ bx, const uint32_t* __restrict__ bwg,
    const float* __restrict__ scaleg, const float* __restrict__ shiftg,
    float* __restrict__ out, int b_start)
{
    int per = gridDim.x >> 3;
    int bid = (blockIdx.x & 7) * per + (blockIdx.x >> 3);

    int h2    = bid & (H2 - 1);
    int plane = bid >> 7;            // local plane [0, nplanes)
    int d     = plane % DD;
    int b     = b_start + plane / DD;
    int w2    = threadIdx.x;

#pragma unroll 1
    for (int rep = 0; rep < REP; ++rep) {
    int acc[16];
#pragma unroll
    for (int c = 0; c < 16; ++c) acc[c] = 0;

#pragma unroll
    for (int kd = 0; kd < 3; ++kd) {
        int dd = d + kd - 1;
        if (dd < 0 || dd >= DD) continue;                 // wave-uniform
        const uint32_t* bxp = bx + (size_t)(plane + kd - 1) * PLANE_WORDS;
#pragma unroll
        for (int kh = 0; kh < 3; ++kh) {
            int hh = h2 + kh - 1;
            if (hh < 0 || hh >= H2) continue;             // wave-uniform
            const uint32_t* brow = bxp + hh * W2;
#pragma unroll
            for (int kw = 0; kw < 3; ++kw) {
                int ww = w2 + kw - 1;
                if (ww >= 0 && ww < W2) {                 // per-lane (edges only)
                    uint32_t word = brow[ww];
                    int tap = kd * 9 + kh * 3 + kw;
#pragma unroll
                    for (int co = 0; co < 16; ++co)
                        acc[co] += __popc(word ^ bwg[tap * 16 + co]);
                }
            }
        }
    }

    int nd = 1 + (d > 0)  + (d < DD - 1);
    int nh = 1 + (h2 > 0) + (h2 < H2 - 1);
    int nw = 1 + (w2 > 0) + (w2 < W2 - 1);
    float base = 32.0f * (float)(nd * nh * nw);

    size_t obase = (((size_t)(b * COUT) * DD + d) * H2 + h2) * W2 + w2;
#pragma unroll
    for (int co = 0; co < 16; ++co) {
        float y = (base - 2.0f * (float)acc[co]) * scaleg[co] + shiftg[co];
        y = y > 0.0f ? y : 0.0f;
        out[obase + (size_t)co * (DD * H2 * W2)] = y;
    }
    }  // rep
}

// ---------------------------------------------------------------------------
// fused: zero-scratch fallback (unchanged from passing rounds).
// ---------------------------------------------------------------------------
__global__ __launch_bounds__(256) void ibc3d_fused(
    const float* __restrict__ x, const float* __restrict__ wgt,
    const float* __restrict__ gamma, const float* __restrict__ beta,
    const float* __restrict__ rmean, const float* __restrict__ rvar,
    float* __restrict__ out)
{
    __shared__ uint32_t sbw[27 * 16];
    __shared__ float sscale[16];
    __shared__ float sshift[16];
    __shared__ uint32_t sw[3][10][264];

    int tid = threadIdx.x;
    for (int t = tid; t < 27 * 16; t += 256) {
        int tap = t >> 4, co = t & 15;
        uint32_t word = 0;
        for (int ci = 0; ci < CIN; ++ci) {
            float v = wgt[(co * CIN + ci) * 27 + tap];
            word |= (v > 0.0f ? 1u : 0u) << ci;
        }
        sbw[t] = word;
    }
    if (tid < 16) {
        int co = tid;
        double s = 0.0;
        for (int i = 0; i < CIN * 27; ++i)
            s += fabs((double)wgt[co * CIN * 27 + i]);
        float alpha = (float)(s / (double)(CIN * 27));
        float inv = gamma[co] / sqrtf(rvar[co] + 1e-5f);
        sscale[co] = alpha * inv;
        sshift[co] = beta[co] - rmean[co] * inv;
    }

    int bid = blockIdx.x;
    int hq  = bid & 15;
    int r   = bid >> 4;
    int b   = r / DD;
    int d   = r % DD;
    int h2base = hq * 8;

    for (int i = tid; i < 3 * 10 * 258; i += 256) {
        int kd  = i / 2580;
        int rem = i - kd * 2580;
        int ri  = rem / 258;
        int ciw = rem - ri * 258;
        int dd = d + kd - 1;
        int h2 = h2base - 1 + ri;
        int w2 = ciw - 1;
        uint32_t word = 0;
        if (dd >= 0 && dd < DD && h2 >= 0 && h2 < H2 && w2 >= 0 && w2 < W2)
            word = pack_word(x, b, dd, h2, w2);
        sw[kd][ri][ciw] = word;
    }
    __syncthreads();

    int w2 = tid;
    for (int p = 0; p < 8; ++p) {
        int h2 = h2base + p;
        int acc[16];
#pragma unroll
        for (int c = 0; c < 16; ++c) acc[c] = 0;
        int nv = 0;
        for (int kd = 0; kd < 3; ++kd) {
            int dd = d + kd - 1;
            if (dd < 0 || dd >= DD) continue;
            for (int kh = 0; kh < 3; ++kh) {
                int hh = h2 + kh - 1;
                if (hh < 0 || hh >= H2) continue;
                for (int kw = 0; kw < 3; ++kw) {
                    int ww = w2 + kw - 1;
                    if (ww < 0 || ww >= W2) continue;
                    uint32_t word = sw[kd][p + kh][w2 + kw];
                    nv += 1;
                    int tap = kd * 9 + kh * 3 + kw;
#pragma unroll
                    for (int co = 0; co < 16; ++co)
                        acc[co] += __popc(word ^ sbw[tap * 16 + co]);
                }
            }
        }
        float base = 32.0f * (float)nv;
#pragma unroll
        for (int co = 0; co < 16; ++co) {
            float y = (base - 2.0f * (float)acc[co]) * sscale[co] + sshift[co];
            y = y > 0.0f ? y : 0.0f;
            size_t oidx = (((size_t)(b * COUT + co) * DD + d) * H2 + h2) * W2 + w2;
            out[oidx] = y;
        }
    }
}

extern "C" void kernel_launch(void* const* d_in, const int* in_sizes, int n_in,
                              void* d_out, int out_size, void* d_ws, size_t ws_size,
                              hipStream_t stream)
{
    (void)in_sizes; (void)n_in; (void)out_size;
    const float* x     = (const float*)d_in[0];
    const float* wgt   = (const float*)d_in[1];
    const float* gamma = (const float*)d_in[2];
    const float* beta  = (const float*)d_in[3];
    const float* rmean = (const float*)d_in[4];
    const float* rvar  = (const float*)d_in[5];
    float* out = (float*)d_out;

    const size_t HDR = 4096;
    const size_t bx_full = (size_t)BB * DD * PLANE_WORDS * 4;  // 12.58 MB
    const size_t bx_half = (size_t)DD * PLANE_WORDS * 4;       //  6.29 MB

    if (d_ws != nullptr && ws_size >= HDR + bx_full) {
        uint8_t* ws = (uint8_t*)d_ws;
        uint32_t* bw    = (uint32_t*)ws;
        float*    scale = (float*)(ws + 2048);
        float*    shift = (float*)(ws + 2112);
        uint32_t* bx    = (uint32_t*)(ws + HDR);
        ibc3d_prep<<<1, 512, 0, stream>>>(wgt, gamma, beta, rmean, rvar, bw, scale, shift);
        int nplanes = BB * DD;                      // 96
        // PROBE ROUND: REP=3 pack / REP=2 conv so each dispatch exceeds the
        // ~115us harness fills and lands in rocprof's top-5 with counters.
        ibc3d_packr8<3><<<nplanes * 16, 256, 0, stream>>>(x, bx, 0, nplanes);
        ibc3d_conv6<2><<<nplanes * H2, 256, 0, stream>>>(bx, bw, scale, shift, out, 0);
    } else if (d_ws != nullptr && ws_size >= HDR + bx_half) {
        uint8_t* ws = (uint8_t*)d_ws;
        uint32_t* bw    = (uint32_t*)ws;
        float*    scale = (float*)(ws + 2048);
        float*    shift = (float*)(ws + 2112);
        uint32_t* bx    = (uint32_t*)(ws + HDR);
        ibc3d_prep<<<1, 512, 0, stream>>>(wgt, gamma, beta, rmean, rvar, bw, scale, shift);
        for (int b = 0; b < BB; ++b) {
            ibc3d_packr8<1><<<DD * 16, 256, 0, stream>>>(x, bx, b, DD);
            ibc3d_conv6<1><<<DD * H2, 256, 0, stream>>>(bx, bw, scale, shift, out, b);
        }
    } else {
        ibc3d_fused<<<BB * DD * (H2 / 8), 256, 0, stream>>>(
            x, wgt, gamma, beta, rmean, rvar, out);
    }
}

// Round 14
// 142.975 us; speedup vs baseline: 1.8749x; 1.8749x over previous
//
#include <hip/hip_runtime.h>
#include <hip/hip_bf16.h>
#include <stdint.h>

// Problem constants
#define BB   2
#define CIN  32
#define COUT 16
#define DD   48
#define HIN  64
#define WIN  128
#define H2   128   // 2*HIN
#define W2   256   // 2*WIN
#define PLANE_WORDS (H2 * W2)   // 32768 sign-words per (b,d) plane

// ---------------------------------------------------------------------------
// prep16: one block per output channel co. Stage the 864-float weight slice
// in LDS (coalesced), LDS-tree fp64 reduce for alpha, threads 0..26 build the
// sign words from LDS. Replaces the 46us single-block serial prep.
// ---------------------------------------------------------------------------
__global__ __launch_bounds__(256) void ibc3d_prep16(
    const float* __restrict__ wgt, const float* __restrict__ gamma,
    const float* __restrict__ beta, const float* __restrict__ rmean,
    const float* __restrict__ rvar, uint32_t* __restrict__ bw,
    float* __restrict__ scale, float* __restrict__ shift)
{
    __shared__ float sw[CIN * 27];      // this co's slice, layout [ci][tap]
    __shared__ double sp[256];

    int co  = blockIdx.x;               // [0,16)
    int tid = threadIdx.x;
    const float* wslice = wgt + (size_t)co * (CIN * 27);

    double p = 0.0;
    for (int i = tid; i < CIN * 27; i += 256) {
        float v = wslice[i];
        sw[i] = v;
        p += fabs((double)v);
    }
    sp[tid] = p;
    __syncthreads();

#pragma unroll
    for (int s = 128; s > 0; s >>= 1) {
        if (tid < s) sp[tid] += sp[tid + s];
        __syncthreads();
    }

    if (tid < 27) {
        int tap = tid;
        uint32_t word = 0;
#pragma unroll
        for (int ci = 0; ci < CIN; ++ci)
            word |= (sw[ci * 27 + tap] > 0.0f ? 1u : 0u) << ci;
        bw[tap * 16 + co] = word;
    }
    if (tid == 0) {
        float alpha = (float)(sp[0] / (double)(CIN * 27));
        float inv = gamma[co] / sqrtf(rvar[co] + 1e-5f);
        scale[co] = alpha * inv;
        shift[co] = beta[co] - rmean[co] * inv;
    }
}

// ---------------------------------------------------------------------------
// pack_word (exact fp64 path, used by fused fallback only).
// ---------------------------------------------------------------------------
__device__ __forceinline__ uint32_t pack_word(const float* __restrict__ x,
                                              int b, int d, int h2, int w2)
{
    int m = h2 >> 1, dh = h2 & 1;
    int n = w2 >> 1, dwp = w2 & 1;
    int rA = m + dh - 1;
    int rB = rA + 1;
    double wA = dh ? 0.75 : 0.25;
    double wB = 1.0 - wA;
    rA = rA < 0 ? 0 : rA;
    rB = rB > (HIN - 1) ? (HIN - 1) : rB;
    int cA = n + dwp - 1;
    int cB = cA + 1;
    double wC = dwp ? 0.75 : 0.25;
    double wD = 1.0 - wC;
    cA = cA < 0 ? 0 : cA;
    cB = cB > (WIN - 1) ? (WIN - 1) : cB;

    const float* xp = x + ((size_t)b * CIN * DD + d) * (HIN * WIN);
    int oA = rA * WIN, oB = rB * WIN;
    uint32_t word = 0;
    for (int ci = 0; ci < CIN; ++ci) {
        const float* xc = xp + (size_t)ci * (DD * HIN * WIN);
        float a0 = xc[oA + cA], a1 = xc[oA + cB];
        float b0 = xc[oB + cA], b1 = xc[oB + cB];
        double t0 = wA * (double)a0 + wB * (double)b0;
        double t1 = wA * (double)a1 + wB * (double)b1;
        double v  = wC * t0 + wD * t1;
        word |= (v >= 0.0 ? 1u : 0u) << ci;
    }
    return word;
}

// ---------------------------------------------------------------------------
// packr8 (measured 20.6us): one thread packs 1 output row x 8 cols.
// fp32 interp, fp64 fallback when any |v| < 1e-5.
// ---------------------------------------------------------------------------
__global__ __launch_bounds__(256) void ibc3d_packr8(
    const float* __restrict__ x, uint32_t* __restrict__ bx,
    int b_start, int nplanes)
{
    int per = gridDim.x >> 3;
    int bid = (blockIdx.x & 7) * per + (blockIdx.x >> 3);
    int idx = bid * 256 + threadIdx.x;   // [0, nplanes*4096)
    int j  = idx & 31;               // 8-col group [0,32)
    int h2 = (idx >> 5) & (H2 - 1);  // output row [0,128)
    int pl = idx >> 12;              // local plane
    if (pl >= nplanes) return;
    int d  = pl % DD;
    int b  = b_start + pl / DD;

    int m = h2 >> 1, q = h2 & 1;
    int rT = q ? m : (m > 0 ? m - 1 : 0);
    int rB = q ? (m < HIN - 1 ? m + 1 : HIN - 1) : m;
    float wT = q ? 0.75f : 0.25f;
    float wB = 1.0f - wT;

    int c0 = 4 * j;
    int cl = c0 >= 2 ? c0 - 2 : 0;
    int cr = (c0 + 4 <= WIN - 2) ? c0 + 4 : WIN - 2;

    const float* xp = x + ((size_t)b * CIN * DD + d) * (HIN * WIN);
    int oT = rT * WIN, oB2 = rB * WIN;

    uint32_t w[8];
#pragma unroll
    for (int k = 0; k < 8; ++k) w[k] = 0u;

#pragma unroll 2
    for (int ci = 0; ci < CIN; ++ci) {
        const float* xc = xp + (size_t)ci * (DD * HIN * WIN);
        float cT[6], cB[6];
        {
            const float* rowT = xc + oT;
            float2 L = *(const float2*)(rowT + cl);
            float4 M = *(const float4*)(rowT + c0);
            float2 R = *(const float2*)(rowT + cr);
            cT[0] = (j > 0)  ? L.y : L.x;
            cT[1] = M.x; cT[2] = M.y; cT[3] = M.z; cT[4] = M.w;
            cT[5] = (j < 31) ? R.x : R.y;
        }
        {
            const float* rowB = xc + oB2;
            float2 L = *(const float2*)(rowB + cl);
            float4 M = *(const float4*)(rowB + c0);
            float2 R = *(const float2*)(rowB + cr);
            cB[0] = (j > 0)  ? L.y : L.x;
            cB[1] = M.x; cB[2] = M.y; cB[3] = M.z; cB[4] = M.w;
            cB[5] = (j < 31) ? R.x : R.y;
        }

        float v[8];
#pragma unroll
        for (int t = 0; t < 4; ++t) {
            float uT0 = 0.25f * cT[t]     + 0.75f * cT[t + 1];
            float uT1 = 0.75f * cT[t + 1] + 0.25f * cT[t + 2];
            float uB0 = 0.25f * cB[t]     + 0.75f * cB[t + 1];
            float uB1 = 0.75f * cB[t + 1] + 0.25f * cB[t + 2];
            v[2 * t]     = wT * uT0 + wB * uB0;
            v[2 * t + 1] = wT * uT1 + wB * uB1;
        }

        float amin = 3.4e38f;
#pragma unroll
        for (int k = 0; k < 8; ++k)
            amin = fminf(amin, fabsf(v[k]));

        if (__builtin_expect(amin < 1e-5f, 0)) {
            double dwT = (double)wT, dwB = 1.0 - (double)wT;
#pragma unroll
            for (int t = 0; t < 4; ++t) {
                double eT0 = 0.25 * (double)cT[t]     + 0.75 * (double)cT[t + 1];
                double eT1 = 0.75 * (double)cT[t + 1] + 0.25 * (double)cT[t + 2];
                double eB0 = 0.25 * (double)cB[t]     + 0.75 * (double)cB[t + 1];
                double eB1 = 0.75 * (double)cB[t + 1] + 0.25 * (double)cB[t + 2];
                uint32_t s0 = (dwT * eT0 + dwB * eB0) >= 0.0;
                uint32_t s1 = (dwT * eT1 + dwB * eB1) >= 0.0;
                w[2 * t]     |= s0 << ci;
                w[2 * t + 1] |= s1 << ci;
            }
        } else {
#pragma unroll
            for (int k = 0; k < 8; ++k)
                w[k] |= (v[k] >= 0.0f ? 1u : 0u) << ci;
        }
    }

    size_t base = (size_t)pl * PLANE_WORDS + (size_t)h2 * W2 + 8 * j;
    *(uint4*)(bx + base)     = make_uint4(w[0], w[1], w[2], w[3]);
    *(uint4*)(bx + base + 4) = make_uint4(w[4], w[5], w[6], w[7]);
}

// ---------------------------------------------------------------------------
// conv3 (measured 70.9us, verbatim; NO swizzle — swizzle measured -9us worse).
// One thread = one (plane, h2, w2), all 16 co; wave-uniform weight reads.
// ---------------------------------------------------------------------------
__global__ __launch_bounds__(256) void ibc3d_conv3(
    const uint32_t* __restrict__ bx, const uint32_t* __restrict__ bwg,
    const float* __restrict__ scaleg, const float* __restrict__ shiftg,
    float* __restrict__ out, int b_start)
{
    int bid   = blockIdx.x;          // plane*128 + h2
    int h2    = bid & (H2 - 1);
    int plane = bid >> 7;            // local plane [0, nplanes)
    int d     = plane % DD;
    int b     = b_start + plane / DD;
    int w2    = threadIdx.x;

    int acc[16];
#pragma unroll
    for (int c = 0; c < 16; ++c) acc[c] = 0;

#pragma unroll
    for (int kd = 0; kd < 3; ++kd) {
        int dd = d + kd - 1;
        if (dd < 0 || dd >= DD) continue;                 // wave-uniform
        const uint32_t* bxp = bx + (size_t)(plane + kd - 1) * PLANE_WORDS;
#pragma unroll
        for (int kh = 0; kh < 3; ++kh) {
            int hh = h2 + kh - 1;
            if (hh < 0 || hh >= H2) continue;             // wave-uniform
            const uint32_t* brow = bxp + hh * W2;
#pragma unroll
            for (int kw = 0; kw < 3; ++kw) {
                int ww = w2 + kw - 1;
                if (ww >= 0 && ww < W2) {                 // per-lane (edges only)
                    uint32_t word = brow[ww];
                    int tap = kd * 9 + kh * 3 + kw;
#pragma unroll
                    for (int co = 0; co < 16; ++co)
                        acc[co] += __popc(word ^ bwg[tap * 16 + co]);
                }
            }
        }
    }

    int nd = 1 + (d > 0)  + (d < DD - 1);
    int nh = 1 + (h2 > 0) + (h2 < H2 - 1);
    int nw = 1 + (w2 > 0) + (w2 < W2 - 1);
    float base = 32.0f * (float)(nd * nh * nw);

    size_t obase = (((size_t)(b * COUT) * DD + d) * H2 + h2) * W2 + w2;
#pragma unroll
    for (int co = 0; co < 16; ++co) {
        float y = (base - 2.0f * (float)acc[co]) * scaleg[co] + shiftg[co];
        y = y > 0.0f ? y : 0.0f;
        out[obase + (size_t)co * (DD * H2 * W2)] = y;
    }
}

// ---------------------------------------------------------------------------
// fused: zero-scratch fallback (unchanged from passing rounds).
// ---------------------------------------------------------------------------
__global__ __launch_bounds__(256) void ibc3d_fused(
    const float* __restrict__ x, const float* __restrict__ wgt,
    const float* __restrict__ gamma, const float* __restrict__ beta,
    const float* __restrict__ rmean, const float* __restrict__ rvar,
    float* __restrict__ out)
{
    __shared__ uint32_t sbw[27 * 16];
    __shared__ float sscale[16];
    __shared__ float sshift[16];
    __shared__ uint32_t sw[3][10][264];

    int tid = threadIdx.x;
    for (int t = tid; t < 27 * 16; t += 256) {
        int tap = t >> 4, co = t & 15;
        uint32_t word = 0;
        for (int ci = 0; ci < CIN; ++ci) {
            float v = wgt[(co * CIN + ci) * 27 + tap];
            word |= (v > 0.0f ? 1u : 0u) << ci;
        }
        sbw[t] = word;
    }
    if (tid < 16) {
        int co = tid;
        double s = 0.0;
        for (int i = 0; i < CIN * 27; ++i)
            s += fabs((double)wgt[co * CIN * 27 + i]);
        float alpha = (float)(s / (double)(CIN * 27));
        float inv = gamma[co] / sqrtf(rvar[co] + 1e-5f);
        sscale[co] = alpha * inv;
        sshift[co] = beta[co] - rmean[co] * inv;
    }

    int bid = blockIdx.x;
    int hq  = bid & 15;
    int r   = bid >> 4;
    int b   = r / DD;
    int d   = r % DD;
    int h2base = hq * 8;

    for (int i = tid; i < 3 * 10 * 258; i += 256) {
        int kd  = i / 2580;
        int rem = i - kd * 2580;
        int ri  = rem / 258;
        int ciw = rem - ri * 258;
        int dd = d + kd - 1;
        int h2 = h2base - 1 + ri;
        int w2 = ciw - 1;
        uint32_t word = 0;
        if (dd >= 0 && dd < DD && h2 >= 0 && h2 < H2 && w2 >= 0 && w2 < W2)
            word = pack_word(x, b, dd, h2, w2);
        sw[kd][ri][ciw] = word;
    }
    __syncthreads();

    int w2 = tid;
    for (int p = 0; p < 8; ++p) {
        int h2 = h2base + p;
        int acc[16];
#pragma unroll
        for (int c = 0; c < 16; ++c) acc[c] = 0;
        int nv = 0;
        for (int kd = 0; kd < 3; ++kd) {
            int dd = d + kd - 1;
            if (dd < 0 || dd >= DD) continue;
            for (int kh = 0; kh < 3; ++kh) {
                int hh = h2 + kh - 1;
                if (hh < 0 || hh >= H2) continue;
                for (int kw = 0; kw < 3; ++kw) {
                    int ww = w2 + kw - 1;
                    if (ww < 0 || ww >= W2) continue;
                    uint32_t word = sw[kd][p + kh][w2 + kw];
                    nv += 1;
                    int tap = kd * 9 + kh * 3 + kw;
#pragma unroll
                    for (int co = 0; co < 16; ++co)
                        acc[co] += __popc(word ^ sbw[tap * 16 + co]);
                }
            }
        }
        float base = 32.0f * (float)nv;
#pragma unroll
        for (int co = 0; co < 16; ++co) {
            float y = (base - 2.0f * (float)acc[co]) * sscale[co] + sshift[co];
            y = y > 0.0f ? y : 0.0f;
            size_t oidx = (((size_t)(b * COUT + co) * DD + d) * H2 + h2) * W2 + w2;
            out[oidx] = y;
        }
    }
}

extern "C" void kernel_launch(void* const* d_in, const int* in_sizes, int n_in,
                              void* d_out, int out_size, void* d_ws, size_t ws_size,
                              hipStream_t stream)
{
    (void)in_sizes; (void)n_in; (void)out_size;
    const float* x     = (const float*)d_in[0];
    const float* wgt   = (const float*)d_in[1];
    const float* gamma = (const float*)d_in[2];
    const float* beta  = (const float*)d_in[3];
    const float* rmean = (const float*)d_in[4];
    const float* rvar  = (const float*)d_in[5];
    float* out = (float*)d_out;

    const size_t HDR = 4096;
    const size_t bx_full = (size_t)BB * DD * PLANE_WORDS * 4;  // 12.58 MB
    const size_t bx_half = (size_t)DD * PLANE_WORDS * 4;       //  6.29 MB

    if (d_ws != nullptr && ws_size >= HDR + bx_full) {
        uint8_t* ws = (uint8_t*)d_ws;
        uint32_t* bw    = (uint32_t*)ws;
        float*    scale = (float*)(ws + 2048);
        float*    shift = (float*)(ws + 2112);
        uint32_t* bx    = (uint32_t*)(ws + HDR);
        ibc3d_prep16<<<16, 256, 0, stream>>>(wgt, gamma, beta, rmean, rvar, bw, scale, shift);
        int nplanes = BB * DD;                      // 96
        ibc3d_packr8<<<nplanes * 16, 256, 0, stream>>>(x, bx, 0, nplanes);
        ibc3d_conv3<<<nplanes * H2, 256, 0, stream>>>(bx, bw, scale, shift, out, 0);
    } else if (d_ws != nullptr && ws_size >= HDR + bx_half) {
        uint8_t* ws = (uint8_t*)d_ws;
        uint32_t* bw    = (uint32_t*)ws;
        float*    scale = (float*)(ws + 2048);
        float*    shift = (float*)(ws + 2112);
        uint32_t* bx    = (uint32_t*)(ws + HDR);
        ibc3d_prep16<<<16, 256, 0, stream>>>(wgt, gamma, beta, rmean, rvar, bw, scale, shift);
        for (int b = 0; b < BB; ++b) {
            ibc3d_packr8<<<DD * 16, 256, 0, stream>>>(x, bx, b, DD);
            ibc3d_conv3<<<DD * H2, 256, 0, stream>>>(bx, bw, scale, shift, out, b);
        }
    } else {
        ibc3d_fused<<<BB * DD * (H2 / 8), 256, 0, stream>>>(
            x, wgt, gamma, beta, rmean, rvar, out);
    }
}